// Round 3
// baseline (450.688 us; speedup 1.0000x reference)
//
#include <hip/hip_runtime.h>

typedef unsigned short u16;
typedef __attribute__((ext_vector_type(8))) short short8;
typedef __attribute__((ext_vector_type(4))) float f32x4;

#define DIM 512
#define CTX 768
#define HW 4096
#define NB 16
#define NS 256
#define EPSV 1e-5f

__device__ inline u16 f2bf(float f) {
    union { float f; unsigned u; } x; x.f = f;
    unsigned r = x.u + 0x7fffu + ((x.u >> 16) & 1u);
    return (u16)(r >> 16);
}
__device__ inline float bf2f(u16 v) {
    union { unsigned u; float f; } x; x.u = (unsigned)v << 16; return x.f;
}

// ---------------- GroupNorm stats: per (b,g) mean/var -> per-channel a,d ----
__global__ void gn_stats(const float* __restrict__ x, const float* __restrict__ gn_w,
                         const float* __restrict__ gn_b, float* __restrict__ ga,
                         float* __restrict__ gd) {
    const int bg = blockIdx.x;           // b*32 + g
    const int b = bg >> 5, g = bg & 31;
    const float* base = x + ((long)b * DIM + g * 16) * HW;
    float s1 = 0.f, s2 = 0.f;
    const int tid = threadIdx.x;
    for (int i = tid; i < 16384; i += 256) {
        float4 v = ((const float4*)base)[i];
        s1 += v.x + v.y + v.z + v.w;
        s2 += v.x * v.x + v.y * v.y + v.z * v.z + v.w * v.w;
    }
    __shared__ float r1[256], r2[256];
    r1[tid] = s1; r2[tid] = s2; __syncthreads();
    for (int s = 128; s > 0; s >>= 1) {
        if (tid < s) { r1[tid] += r1[tid + s]; r2[tid] += r2[tid + s]; }
        __syncthreads();
    }
    __shared__ float mu_s, rs_s;
    if (tid == 0) {
        float mu = r1[0] * (1.f / 65536.f);
        float var = r2[0] * (1.f / 65536.f) - mu * mu;
        mu_s = mu; rs_s = rsqrtf(var + EPSV);
    }
    __syncthreads();
    if (tid < 16) {
        int c = g * 16 + tid;
        float aa = rs_s * gn_w[c];
        ga[b * DIM + c] = aa;
        gd[b * DIM + c] = gn_b[c] - mu_s * aa;
    }
}

// ------------- GN apply + transpose: x(b,c,p) -> xn_t(b,p,c) bf16 ----------
// 64x64 tile, float4 reads, short8 (16B) writes.
__global__ void gn_apply_t(const float* __restrict__ x, const float* __restrict__ ga,
                           const float* __restrict__ gd, u16* __restrict__ xnt) {
    const int b = blockIdx.y;
    const int c0 = (blockIdx.x & 7) * 64;
    const int p0 = (blockIdx.x >> 3) * 64;
    __shared__ u16 t[64][68];
    const int tid = threadIdx.x;
    const int tc = tid >> 4;        // 0..15
    const int tp = (tid & 15) * 4;  // 0..60
    #pragma unroll
    for (int i = 0; i < 4; i++) {
        const int c = c0 + tc + i * 16;
        const float a = ga[b * DIM + c];
        const float d = gd[b * DIM + c];
        float4 v = *(const float4*)&x[((long)b * DIM + c) * HW + p0 + tp];
        u16* dst = &t[tc + i * 16][tp];
        dst[0] = f2bf(v.x * a + d);
        dst[1] = f2bf(v.y * a + d);
        dst[2] = f2bf(v.z * a + d);
        dst[3] = f2bf(v.w * a + d);
    }
    __syncthreads();
    const int wp = tid >> 3;        // 0..31
    const int wc = (tid & 7) * 8;   // 0..56
    #pragma unroll
    for (int i = 0; i < 2; i++) {
        const int p = wp + i * 32;
        short8 o;
        #pragma unroll
        for (int k = 0; k < 8; k++) o[k] = t[wc + k][p];
        *(short8*)&xnt[((long)b * HW + p0 + p) * DIM + c0 + wc] = o;
    }
}

// ------------- LayerNorm on context -> cn bf16 (b, s, 768) -----------------
__global__ void ln_ctx(const float* __restrict__ ctx, const float* __restrict__ ln_w,
                       const float* __restrict__ ln_b, u16* __restrict__ cn) {
    const int row = blockIdx.x;  // b*256 + s
    const int tid = threadIdx.x;
    const float* r = ctx + (long)row * CTX;
    float v[3]; float s1 = 0.f, s2 = 0.f;
    #pragma unroll
    for (int i = 0; i < 3; i++) { v[i] = r[tid + i * 256]; s1 += v[i]; s2 += v[i] * v[i]; }
    __shared__ float r1[256], r2[256];
    r1[tid] = s1; r2[tid] = s2; __syncthreads();
    for (int s = 128; s > 0; s >>= 1) {
        if (tid < s) { r1[tid] += r1[tid + s]; r2[tid] += r2[tid + s]; }
        __syncthreads();
    }
    __shared__ float mu_s, rs_s;
    if (tid == 0) {
        float mu = r1[0] * (1.f / 768.f);
        float var = r2[0] * (1.f / 768.f) - mu * mu;
        mu_s = mu; rs_s = rsqrtf(var + EPSV);
    }
    __syncthreads();
    #pragma unroll
    for (int i = 0; i < 3; i++) {
        int idx = tid + i * 256;
        cn[(long)row * CTX + idx] = f2bf((v[i] - mu_s) * rs_s * ln_w[idx] + ln_b[idx]);
    }
}

// ------------- weights fp32 -> bf16 (wq transposed: wqt[c][o] = wq[o][c]) ---
__global__ void cvt_weights(const float* __restrict__ wq, const float* __restrict__ wkv,
                            const float* __restrict__ wo, u16* __restrict__ wqtb,
                            u16* __restrict__ wkvb, u16* __restrict__ wob) {
    int i = blockIdx.x * 256 + threadIdx.x;
    if (i < 262144) {
        wqtb[(i & 511) * 512 + (i >> 9)] = f2bf(wq[i]);
        wob[i] = f2bf(wo[i]);
    }
    if (i < 786432) wkvb[i] = f2bf(wkv[i]);
}

// ------------- kbias[b*NS+s] = dot(k[b,s,:], bq) ---------------------------
__global__ void kbias_k(const u16* __restrict__ k, const float* __restrict__ bq,
                        float* __restrict__ kbias) {
    const int row = blockIdx.x;
    const int tid = threadIdx.x;
    const u16* r = k + (long)row * DIM;
    float s = bf2f(r[tid]) * bq[tid] + bf2f(r[tid + 256]) * bq[tid + 256];
    __shared__ float red[256];
    red[tid] = s; __syncthreads();
    for (int st = 128; st > 0; st >>= 1) {
        if (tid < st) red[tid] += red[tid + st];
        __syncthreads();
    }
    if (tid == 0) kbias[row] = red[0];
}

// ------------- kv GEMM: kv = cn(256x768) @ wkv^T, split k/v, +bkv ----------
// 128x128 tile, register-prefetch 2-phase pipeline.
__launch_bounds__(256, 2)
__global__ void gemm_kv(const u16* __restrict__ A, const u16* __restrict__ Bm,
                        const float* __restrict__ bias,
                        u16* __restrict__ outk, u16* __restrict__ outv) {
    __shared__ u16 As[128][56];
    __shared__ u16 Bs[128][56];
    const int tid = threadIdx.x;
    const int lane = tid & 63;
    const int wave = tid >> 6;
    const int bb = blockIdx.y;
    const int m0 = (blockIdx.x >> 3) << 7;   // 2 m-tiles (NS=256)
    const int n0 = (blockIdx.x & 7) << 7;    // 8 n-tiles (2*DIM=1024)
    const u16* Ab = A + (long)bb * NS * CTX + (long)m0 * CTX;
    const u16* Bb = Bm + (long)n0 * CTX;

    const int sr = tid >> 2;          // 0..63
    const int sc = (tid & 3) << 3;    // 0,8,16,24
    const int l16 = lane & 15;
    const int quad = lane >> 4;
    const int wr = (wave >> 1) << 6;
    const int wc = (wave & 1) << 6;

    const u16* Ap0 = Ab + (long)sr * CTX + sc;
    const u16* Ap1 = Ab + (long)(sr + 64) * CTX + sc;
    const u16* Bp0 = Bb + (long)sr * CTX + sc;
    const u16* Bp1 = Bb + (long)(sr + 64) * CTX + sc;
    short8 rA0 = *(const short8*)Ap0;
    short8 rA1 = *(const short8*)Ap1;
    short8 rB0 = *(const short8*)Bp0;
    short8 rB1 = *(const short8*)Bp1;

    f32x4 acc[4][4] = {};
    for (int k0 = 0; k0 < CTX; k0 += 32) {
        if (k0) __syncthreads();
        *(short8*)&As[sr][sc]      = rA0;
        *(short8*)&As[sr + 64][sc] = rA1;
        *(short8*)&Bs[sr][sc]      = rB0;
        *(short8*)&Bs[sr + 64][sc] = rB1;
        __syncthreads();
        if (k0 + 32 < CTX) {
            rA0 = *(const short8*)(Ap0 + k0 + 32);
            rA1 = *(const short8*)(Ap1 + k0 + 32);
            rB0 = *(const short8*)(Bp0 + k0 + 32);
            rB1 = *(const short8*)(Bp1 + k0 + 32);
        }
        short8 af[4], bfr[4];
        #pragma unroll
        for (int i = 0; i < 4; i++) af[i] = *(const short8*)&As[wr + i * 16 + l16][quad * 8];
        #pragma unroll
        for (int j = 0; j < 4; j++) bfr[j] = *(const short8*)&Bs[wc + j * 16 + l16][quad * 8];
        #pragma unroll
        for (int i = 0; i < 4; i++)
            #pragma unroll
            for (int j = 0; j < 4; j++)
                acc[i][j] = __builtin_amdgcn_mfma_f32_16x16x32_bf16(af[i], bfr[j], acc[i][j], 0, 0, 0);
    }

    #pragma unroll
    for (int i = 0; i < 4; i++) {
        #pragma unroll
        for (int r = 0; r < 4; r++) {
            const int row = m0 + wr + i * 16 + quad * 4 + r;
            #pragma unroll
            for (int j = 0; j < 4; j++) {
                const int col = n0 + wc + j * 16 + l16;
                float v = acc[i][j][r] + bias[col];
                if (col < DIM) outk[(long)bb * NS * DIM + (long)row * DIM + col] = f2bf(v);
                else           outv[(long)bb * NS * DIM + (long)row * DIM + (col - DIM)] = f2bf(v);
            }
        }
    }
}

// ------------- merged Q/V GEMM: z=0: Kq = k @ wqt^T (row-major out)
//               z=1: Vot = (v @ wo^T)^T (transposed out) -------------------
__launch_bounds__(256, 2)
__global__ void gemm_qv(const u16* __restrict__ kb_, const u16* __restrict__ vb_,
                        const u16* __restrict__ wqtb, const u16* __restrict__ wob,
                        u16* __restrict__ Kq, u16* __restrict__ Vot) {
    __shared__ u16 As[128][56];
    __shared__ u16 Bs[128][56];
    const int tid = threadIdx.x;
    const int lane = tid & 63;
    const int wave = tid >> 6;
    const int bb = blockIdx.y;
    const bool isV = blockIdx.z != 0;
    const int m0 = (blockIdx.x >> 2) << 7;   // 2 m-tiles (NS=256)
    const int n0 = (blockIdx.x & 3) << 7;    // 4 n-tiles (DIM=512)
    const u16* Ab = (isV ? vb_ : kb_) + (long)bb * NS * DIM + (long)m0 * DIM;
    const u16* Bb = (isV ? wob : wqtb) + (long)n0 * DIM;

    const int sr = tid >> 2;
    const int sc = (tid & 3) << 3;
    const int l16 = lane & 15;
    const int quad = lane >> 4;
    const int wr = (wave >> 1) << 6;
    const int wc = (wave & 1) << 6;

    const u16* Ap0 = Ab + (long)sr * DIM + sc;
    const u16* Ap1 = Ab + (long)(sr + 64) * DIM + sc;
    const u16* Bp0 = Bb + (long)sr * DIM + sc;
    const u16* Bp1 = Bb + (long)(sr + 64) * DIM + sc;
    short8 rA0 = *(const short8*)Ap0;
    short8 rA1 = *(const short8*)Ap1;
    short8 rB0 = *(const short8*)Bp0;
    short8 rB1 = *(const short8*)Bp1;

    f32x4 acc[4][4] = {};
    for (int k0 = 0; k0 < DIM; k0 += 32) {
        if (k0) __syncthreads();
        *(short8*)&As[sr][sc]      = rA0;
        *(short8*)&As[sr + 64][sc] = rA1;
        *(short8*)&Bs[sr][sc]      = rB0;
        *(short8*)&Bs[sr + 64][sc] = rB1;
        __syncthreads();
        if (k0 + 32 < DIM) {
            rA0 = *(const short8*)(Ap0 + k0 + 32);
            rA1 = *(const short8*)(Ap1 + k0 + 32);
            rB0 = *(const short8*)(Bp0 + k0 + 32);
            rB1 = *(const short8*)(Bp1 + k0 + 32);
        }
        short8 af[4], bfr[4];
        #pragma unroll
        for (int i = 0; i < 4; i++) af[i] = *(const short8*)&As[wr + i * 16 + l16][quad * 8];
        #pragma unroll
        for (int j = 0; j < 4; j++) bfr[j] = *(const short8*)&Bs[wc + j * 16 + l16][quad * 8];
        #pragma unroll
        for (int i = 0; i < 4; i++)
            #pragma unroll
            for (int j = 0; j < 4; j++)
                acc[i][j] = __builtin_amdgcn_mfma_f32_16x16x32_bf16(af[i], bfr[j], acc[i][j], 0, 0, 0);
    }

    #pragma unroll
    for (int i = 0; i < 4; i++) {
        #pragma unroll
        for (int r = 0; r < 4; r++) {
            const int row = m0 + wr + i * 16 + quad * 4 + r;
            #pragma unroll
            for (int j = 0; j < 4; j++) {
                const int col = n0 + wc + j * 16 + l16;
                const u16 v = f2bf(acc[i][j][r]);
                if (!isV) Kq[(long)bb * NS * DIM + (long)row * DIM + col] = v;
                else      Vot[(long)bb * DIM * NS + (long)col * NS + row] = v;
            }
        }
    }
}

// ------------- fused attention: S = xn@Kq^T, softmax, O = P@Vot^T ----------
// block: 512 thr (8 waves, 2m x 4n), 128 q-rows, full NS=256 cols.
// LDS (69632 B -> 2 blocks/CU):
//   [0, 43008)   As 128x56 + Bs 256x56  (S-phase staging, dead after S)
//   [0, 67584)   P 128x264 bf16         (aliases As/Bs; written post-S)
//   [67584, 69632)  red 128x4 f32
// S-phase: 2-phase register-prefetch pipeline (global latency hidden under MFMA).
// PV + epilogue: ZERO barriers — V read from global (L2-resident, 256KB/batch),
// O written directly from accumulators as float4 (lane holds 4 consecutive p).
__launch_bounds__(512, 4)
__global__ void flash_attn(const u16* __restrict__ xnt, const u16* __restrict__ Kq,
                           const u16* __restrict__ Vot, const float* __restrict__ kbias,
                           const float* __restrict__ bo, const float* __restrict__ x,
                           float* __restrict__ out) {
    __shared__ __align__(16) char fsm[69632];
    u16 (*As)[56]      = (u16(*)[56])(fsm);
    u16 (*Bs)[56]      = (u16(*)[56])(fsm + 14336);
    u16 (*P)[264]      = (u16(*)[264])(fsm);            // aliases As/Bs
    float (*red)[4]    = (float(*)[4])(fsm + 67584);

    const int tid = threadIdx.x;
    const int lane = tid & 63;
    const int wave = tid >> 6;   // 0..7
    const int mw = wave >> 2;    // 0..1  (row group of 64)
    const int nw = wave & 3;     // 0..3  (col group of 64)
    const int l16 = lane & 15;
    const int quad = lane >> 4;
    const int b = blockIdx.y;
    const int m0 = blockIdx.x << 7;

    const u16* Ab = xnt + ((long)b * HW + m0) * DIM;
    const u16* Bb = Kq + (long)b * NS * DIM;

    // ---------------- S phase (pipelined) ----------------
    const int rS = tid >> 2, cS = (tid & 3) << 3;
    const int rB = tid >> 1, cB = (tid & 1) << 4;
    const u16* Ap = Ab + (long)rS * DIM + cS;
    const u16* Bp = Bb + (long)rB * DIM + cB;
    short8 rA  = *(const short8*)(Ap);
    short8 rB0 = *(const short8*)(Bp);
    short8 rB1 = *(const short8*)(Bp + 8);

    f32x4 acc[4][4] = {};
    for (int k0 = 0; k0 < DIM; k0 += 32) {
        if (k0) __syncthreads();          // prior iter's fragment reads done
        *(short8*)&As[rS][cS]     = rA;
        *(short8*)&Bs[rB][cB]     = rB0;
        *(short8*)&Bs[rB][cB + 8] = rB1;
        __syncthreads();
        if (k0 + 32 < DIM) {              // prefetch next tile (hidden under MFMA)
            rA  = *(const short8*)(Ap + k0 + 32);
            rB0 = *(const short8*)(Bp + k0 + 32);
            rB1 = *(const short8*)(Bp + k0 + 40);
        }
        short8 af[4], bfr[4];
        #pragma unroll
        for (int i = 0; i < 4; i++) af[i] = *(const short8*)&As[mw * 64 + i * 16 + l16][quad * 8];
        #pragma unroll
        for (int j = 0; j < 4; j++) bfr[j] = *(const short8*)&Bs[nw * 64 + j * 16 + l16][quad * 8];
        #pragma unroll
        for (int i = 0; i < 4; i++)
            #pragma unroll
            for (int j = 0; j < 4; j++)
                acc[i][j] = __builtin_amdgcn_mfma_f32_16x16x32_bf16(af[i], bfr[j], acc[i][j], 0, 0, 0);
    }

    // ---------------- softmax ----------------
    const float scale = 0.044194173824159216f;
    float kb[4];
    #pragma unroll
    for (int j = 0; j < 4; j++) kb[j] = kbias[b * NS + nw * 64 + j * 16 + l16];

    // scale+bias, per-wave row max, publish to red[row][nw]
    #pragma unroll
    for (int i = 0; i < 4; i++) {
        #pragma unroll
        for (int r = 0; r < 4; r++) {
            float m = -1e30f;
            #pragma unroll
            for (int j = 0; j < 4; j++) {
                float v = (acc[i][j][r] + kb[j]) * scale;
                acc[i][j][r] = v;
                m = fmaxf(m, v);
            }
            #pragma unroll
            for (int off = 1; off < 16; off <<= 1) m = fmaxf(m, __shfl_xor(m, off));
            if (l16 == 0) red[mw * 64 + i * 16 + quad * 4 + r][nw] = m;
        }
    }
    __syncthreads();          // also: last As/Bs fragment reads done block-wide
    // global row max, exp, per-wave row sum
    float rsum[4][4];
    #pragma unroll
    for (int i = 0; i < 4; i++) {
        #pragma unroll
        for (int r = 0; r < 4; r++) {
            const int row = mw * 64 + i * 16 + quad * 4 + r;
            float4 rv = *(const float4*)red[row];
            float gm = fmaxf(fmaxf(rv.x, rv.y), fmaxf(rv.z, rv.w));
            float s = 0.f;
            #pragma unroll
            for (int j = 0; j < 4; j++) {
                float e = __expf(acc[i][j][r] - gm);
                acc[i][j][r] = e;
                s += e;
            }
            #pragma unroll
            for (int off = 1; off < 16; off <<= 1) s += __shfl_xor(s, off);
            rsum[i][r] = s;
        }
    }
    __syncthreads();
    #pragma unroll
    for (int i = 0; i < 4; i++)
        #pragma unroll
        for (int r = 0; r < 4; r++)
            if (l16 == 0) red[mw * 64 + i * 16 + quad * 4 + r][nw] = rsum[i][r];
    __syncthreads();
    // normalize + write P (bf16) to LDS (safe: stage region dead since barrier)
    #pragma unroll
    for (int i = 0; i < 4; i++) {
        #pragma unroll
        for (int r = 0; r < 4; r++) {
            const int row = mw * 64 + i * 16 + quad * 4 + r;
            float4 sv = *(const float4*)red[row];
            float inv = 1.f / (sv.x + sv.y + sv.z + sv.w);
            #pragma unroll
            for (int j = 0; j < 4; j++)
                P[row][nw * 64 + j * 16 + l16] = f2bf(acc[i][j][r] * inv);
        }
    }
    __syncthreads();   // P ready for all waves — LAST barrier in the kernel

    // -------- PV phase: 4 chunks of 128 out-channels, barrier-free ---------
    const u16* Vb = Vot + ((long)b * DIM + nw * 32 + l16) * NS + quad * 8;
    for (int nc = 0; nc < 4; nc++) {
        f32x4 oacc[4][2];
        #pragma unroll
        for (int i = 0; i < 4; i++)
            #pragma unroll
            for (int jj = 0; jj < 2; jj++)
                oacc[i][jj] = (f32x4){0.f, 0.f, 0.f, 0.f};
        #pragma unroll
        for (int kk = 0; kk < 8; kk++) {
            short8 pf[4], vf[2];
            #pragma unroll
            for (int i = 0; i < 4; i++)
                pf[i] = *(const short8*)&P[mw * 64 + i * 16 + l16][kk * 32 + quad * 8];
            #pragma unroll
            for (int jj = 0; jj < 2; jj++)
                vf[jj] = *(const short8*)(Vb + (long)(nc * 128 + jj * 16) * NS + kk * 32);
            #pragma unroll
            for (int i = 0; i < 4; i++)
                #pragma unroll
                for (int jj = 0; jj < 2; jj++)
                    oacc[i][jj] = __builtin_amdgcn_mfma_f32_16x16x32_bf16(pf[i], vf[jj], oacc[i][jj], 0, 0, 0);
        }
        // direct epilogue: lane holds 4 consecutive p for channel c.
        // out[b][c][p..p+3] = oacc + bo[c] + x[...]  (float4, no LDS, no barriers)
        #pragma unroll
        for (int jj = 0; jj < 2; jj++) {
            const int c = nc * 128 + nw * 32 + jj * 16 + l16;
            const float bv = bo[c];
            const long base = ((long)b * DIM + c) * HW + m0 + mw * 64 + quad * 4;
            #pragma unroll
            for (int i = 0; i < 4; i++) {
                float4 xv = *(const float4*)&x[base + i * 16];
                float4 o;
                o.x = oacc[i][jj][0] + xv.x + bv;
                o.y = oacc[i][jj][1] + xv.y + bv;
                o.z = oacc[i][jj][2] + xv.z + bv;
                o.w = oacc[i][jj][3] + xv.w + bv;
                *(float4*)&out[base + i * 16] = o;
            }
        }
    }
}

extern "C" void kernel_launch(void* const* d_in, const int* in_sizes, int n_in,
                              void* d_out, int out_size, void* d_ws, size_t ws_size,
                              hipStream_t stream) {
    const float* x    = (const float*)d_in[0];
    const float* ctx  = (const float*)d_in[1];
    const float* gn_w = (const float*)d_in[2];
    const float* gn_b = (const float*)d_in[3];
    const float* ln_w = (const float*)d_in[4];
    const float* ln_b = (const float*)d_in[5];
    const float* wq   = (const float*)d_in[6];
    const float* bq   = (const float*)d_in[7];
    const float* wkv  = (const float*)d_in[8];
    const float* bkv  = (const float*)d_in[9];
    const float* wo   = (const float*)d_in[10];
    const float* bo   = (const float*)d_in[11];

    char* ws = (char*)d_ws;
    u16*   xnt  = (u16*)(ws + 0);             // 64 MB
    u16*   cn   = (u16*)(ws + 67108864);      //  6 MB
    u16*   kb_  = (u16*)(ws + 73400320);      //  4 MB  (k, row-major b,s,512)
    u16*   vb_  = (u16*)(ws + 77594624);      //  4 MB  (v, row-major b,s,512)
    u16*   Kq   = (u16*)(ws + 81788928);      //  4 MB  (K@wq, b,s,512)
    u16*   Vot  = (u16*)(ws + 85983232);      //  4 MB  ((V@wo^T)^T, b,c',s)
    u16*   wqtb = (u16*)(ws + 90177536);      // 512 KB (wq^T)
    u16*   wkvb = (u16*)(ws + 90701824);      // 1.5 MB
    u16*   wob  = (u16*)(ws + 92274688);      // 512 KB
    float* ga   = (float*)(ws + 92798976);
    float* gd   = ga + NB * DIM;
    float* kbias = (float*)(ws + 92864512);   // 16 KB

    gn_stats<<<dim3(NB * 32), dim3(256), 0, stream>>>(x, gn_w, gn_b, ga, gd);
    gn_apply_t<<<dim3(512, NB), dim3(256), 0, stream>>>(x, ga, gd, xnt);
    ln_ctx<<<dim3(NB * NS), dim3(256), 0, stream>>>(ctx, ln_w, ln_b, cn);
    cvt_weights<<<dim3(3072), dim3(256), 0, stream>>>(wq, wkv, wo, wqtb, wkvb, wob);

    // kv = cn(256x768) @ wkv^T -> k(b,s,512), v(b,s,512)
    gemm_kv<<<dim3(2 * 8, NB), dim3(256), 0, stream>>>(cn, wkvb, bkv, kb_, vb_);
    // z=0: Kq = k @ wq ; z=1: Vot = (v @ wo^T)^T   (merged dispatch)
    gemm_qv<<<dim3(2 * 4, NB, 2), dim3(256), 0, stream>>>(kb_, vb_, wqtb, wob, Kq, Vot);
    kbias_k<<<dim3(NB * NS), dim3(256), 0, stream>>>(kb_, bq, kbias);
    // fused sim + softmax + PV + residual -> d_out (b,c,p) fp32
    flash_attn<<<dim3(32, NB), dim3(512), 0, stream>>>(
        xnt, Kq, Vot, kbias, bo, x, (float*)d_out);
}

// Round 5
// 421.577 us; speedup vs baseline: 1.0691x; 1.0691x over previous
//
#include <hip/hip_runtime.h>

typedef unsigned short u16;
typedef __attribute__((ext_vector_type(8))) short short8;
typedef __attribute__((ext_vector_type(4))) float f32x4;

#define DIM 512
#define CTX 768
#define HW 4096
#define NB 16
#define NS 256
#define EPSV 1e-5f

__device__ inline u16 f2bf(float f) {
    union { float f; unsigned u; } x; x.f = f;
    unsigned r = x.u + 0x7fffu + ((x.u >> 16) & 1u);
    return (u16)(r >> 16);
}
__device__ inline float bf2f(u16 v) {
    union { unsigned u; float f; } x; x.u = (unsigned)v << 16; return x.f;
}

// ---------------- GroupNorm stats: per (b,g) mean/var -> per-channel a,d ----
__global__ void gn_stats(const float* __restrict__ x, const float* __restrict__ gn_w,
                         const float* __restrict__ gn_b, float* __restrict__ ga,
                         float* __restrict__ gd) {
    const int bg = blockIdx.x;           // b*32 + g
    const int b = bg >> 5, g = bg & 31;
    const float* base = x + ((long)b * DIM + g * 16) * HW;
    float s1 = 0.f, s2 = 0.f;
    const int tid = threadIdx.x;
    for (int i = tid; i < 16384; i += 256) {
        float4 v = ((const float4*)base)[i];
        s1 += v.x + v.y + v.z + v.w;
        s2 += v.x * v.x + v.y * v.y + v.z * v.z + v.w * v.w;
    }
    __shared__ float r1[256], r2[256];
    r1[tid] = s1; r2[tid] = s2; __syncthreads();
    for (int s = 128; s > 0; s >>= 1) {
        if (tid < s) { r1[tid] += r1[tid + s]; r2[tid] += r2[tid + s]; }
        __syncthreads();
    }
    __shared__ float mu_s, rs_s;
    if (tid == 0) {
        float mu = r1[0] * (1.f / 65536.f);
        float var = r2[0] * (1.f / 65536.f) - mu * mu;
        mu_s = mu; rs_s = rsqrtf(var + EPSV);
    }
    __syncthreads();
    if (tid < 16) {
        int c = g * 16 + tid;
        float aa = rs_s * gn_w[c];
        ga[b * DIM + c] = aa;
        gd[b * DIM + c] = gn_b[c] - mu_s * aa;
    }
}

// ------------- GN apply + transpose: x(b,c,p) -> xn_t(b,p,c) bf16 ----------
__global__ void gn_apply_t(const float* __restrict__ x, const float* __restrict__ ga,
                           const float* __restrict__ gd, u16* __restrict__ xnt) {
    const int b = blockIdx.y;
    const int c0 = (blockIdx.x & 7) * 64;
    const int p0 = (blockIdx.x >> 3) * 64;
    __shared__ u16 t[64][68];
    const int tid = threadIdx.x;
    const int tc = tid >> 4;        // 0..15
    const int tp = (tid & 15) * 4;  // 0..60
    #pragma unroll
    for (int i = 0; i < 4; i++) {
        const int c = c0 + tc + i * 16;
        const float a = ga[b * DIM + c];
        const float d = gd[b * DIM + c];
        float4 v = *(const float4*)&x[((long)b * DIM + c) * HW + p0 + tp];
        u16* dst = &t[tc + i * 16][tp];
        dst[0] = f2bf(v.x * a + d);
        dst[1] = f2bf(v.y * a + d);
        dst[2] = f2bf(v.z * a + d);
        dst[3] = f2bf(v.w * a + d);
    }
    __syncthreads();
    const int wp = tid >> 3;        // 0..31
    const int wc = (tid & 7) * 8;   // 0..56
    #pragma unroll
    for (int i = 0; i < 2; i++) {
        const int p = wp + i * 32;
        short8 o;
        #pragma unroll
        for (int k = 0; k < 8; k++) o[k] = t[wc + k][p];
        *(short8*)&xnt[((long)b * HW + p0 + p) * DIM + c0 + wc] = o;
    }
}

// ------------- weights fp32 -> bf16: wqtb[c][o]=wq[o][c], wob=wo,
//               wkvtb[e][o]=wkv[o][e] ---------------------------------------
__global__ void cvt_weights(const float* __restrict__ wq, const float* __restrict__ wkv,
                            const float* __restrict__ wo, u16* __restrict__ wqtb,
                            u16* __restrict__ wkvtb, u16* __restrict__ wob) {
    int i = blockIdx.x * 256 + threadIdx.x;
    if (i < 262144) {
        wqtb[(i & 511) * 512 + (i >> 9)] = f2bf(wq[i]);
        wob[i] = f2bf(wo[i]);
    }
    if (i < 786432) {
        int o = i / 768, e = i - o * 768;
        wkvtb[e * 1024 + o] = f2bf(wkv[i]);
    }
}

// ------------- fused bias vectors:
//   bid<512   : bKV[c]   = sum_o bkv[o]     * wq[o][c]   (via wqtb row)
//   bid<1024  : bKV[c]   = sum_d bkv[512+d] * wo[c-512][d] (via wob row)
//   bid<1792  : wt[e]    = sum_d bq[d]      * wkv[d][e]  (via wkvtb row)
//   bid==1792 : c0       = sum_d bq[d]*bkv[d]
__global__ void bias_prep(const u16* __restrict__ wqtb, const u16* __restrict__ wob,
                          const u16* __restrict__ wkvtb, const float* __restrict__ bq,
                          const float* __restrict__ bkv, float* __restrict__ bKV,
                          float* __restrict__ wt, float* __restrict__ c0) {
    const int bid = blockIdx.x, tid = threadIdx.x;
    float s = 0.f;
    if (bid < 512) {
        const u16* r = wqtb + (long)bid * 512;
        s = bf2f(r[tid]) * bkv[tid] + bf2f(r[tid + 256]) * bkv[tid + 256];
    } else if (bid < 1024) {
        const u16* r = wob + (long)(bid - 512) * 512;
        s = bf2f(r[tid]) * bkv[512 + tid] + bf2f(r[tid + 256]) * bkv[512 + tid + 256];
    } else if (bid < 1792) {
        const u16* r = wkvtb + (long)(bid - 1024) * 1024;
        s = bf2f(r[tid]) * bq[tid] + bf2f(r[tid + 256]) * bq[tid + 256];
    } else {
        s = bq[tid] * bkv[tid] + bq[tid + 256] * bkv[tid + 256];
    }
    __shared__ float red[256];
    red[tid] = s; __syncthreads();
    for (int st = 128; st > 0; st >>= 1) {
        if (tid < st) red[tid] += red[tid + st];
        __syncthreads();
    }
    if (tid == 0) {
        if (bid < 1024) bKV[bid] = red[0];
        else if (bid < 1792) wt[bid - 1024] = red[0];
        else *c0 = red[0];
    }
}

// ------------- LayerNorm on context -> cn bf16; also kbias[row] ------------
__global__ void ln_ctx(const float* __restrict__ ctx, const float* __restrict__ ln_w,
                       const float* __restrict__ ln_b, const float* __restrict__ wt,
                       const float* __restrict__ c0, u16* __restrict__ cn,
                       float* __restrict__ kbias) {
    const int row = blockIdx.x;  // b*256 + s
    const int tid = threadIdx.x;
    const float* r = ctx + (long)row * CTX;
    float v[3]; float s1 = 0.f, s2 = 0.f;
    #pragma unroll
    for (int i = 0; i < 3; i++) { v[i] = r[tid + i * 256]; s1 += v[i]; s2 += v[i] * v[i]; }
    __shared__ float r1[256], r2[256];
    r1[tid] = s1; r2[tid] = s2; __syncthreads();
    for (int s = 128; s > 0; s >>= 1) {
        if (tid < s) { r1[tid] += r1[tid + s]; r2[tid] += r2[tid + s]; }
        __syncthreads();
    }
    __shared__ float mu_s, rs_s;
    if (tid == 0) {
        float mu = r1[0] * (1.f / 768.f);
        float var = r2[0] * (1.f / 768.f) - mu * mu;
        mu_s = mu; rs_s = rsqrtf(var + EPSV);
    }
    __syncthreads();
    float kb = 0.f;
    #pragma unroll
    for (int i = 0; i < 3; i++) {
        int idx = tid + i * 256;
        float nv = (v[i] - mu_s) * rs_s * ln_w[idx] + ln_b[idx];
        cn[(long)row * CTX + idx] = f2bf(nv);
        kb += nv * wt[idx];
    }
    r1[tid] = kb; __syncthreads();
    for (int s = 128; s > 0; s >>= 1) {
        if (tid < s) r1[tid] += r1[tid + s];
        __syncthreads();
    }
    if (tid == 0) kbias[row] = r1[0] + *c0;
}

// ------------- weight-prep GEMM: Wt[1024][768] bf16 ------------------------
// z=0: Wt[c][e]     = sum_{o<512} wqtb[c][o] * wkvtb[e][o]        (K-side)
// z=1: Wt[512+c][e] = sum_{d<512} wob[c][d]  * wkvtb[e][512+d]    (V-side)
__launch_bounds__(256, 2)
__global__ void gemm_wprep(const u16* __restrict__ wqtb, const u16* __restrict__ wob,
                           const u16* __restrict__ wkvtb, u16* __restrict__ Wt) {
    __shared__ u16 As[128][56];
    __shared__ u16 Bs[128][56];
    const int tid = threadIdx.x;
    const int lane = tid & 63;
    const int wave = tid >> 6;
    const bool isV = blockIdx.z != 0;
    const int m0 = (blockIdx.x / 6) << 7;    // 512 rows -> 4 m-tiles
    const int n0 = (blockIdx.x % 6) << 7;    // 768 cols -> 6 n-tiles
    const u16* Ab = (isV ? wob : wqtb) + (long)m0 * 512;
    const u16* Bb = wkvtb + (long)n0 * 1024 + (isV ? 512 : 0);
    u16* Ob = Wt + (isV ? (long)512 * 768 : 0);

    const int sr = tid >> 2;
    const int sc = (tid & 3) << 3;
    const int l16 = lane & 15;
    const int quad = lane >> 4;
    const int wr = (wave >> 1) << 6;
    const int wc = (wave & 1) << 6;

    const u16* Ap0 = Ab + (long)sr * 512 + sc;
    const u16* Ap1 = Ab + (long)(sr + 64) * 512 + sc;
    const u16* Bp0 = Bb + (long)sr * 1024 + sc;
    const u16* Bp1 = Bb + (long)(sr + 64) * 1024 + sc;
    short8 rA0 = *(const short8*)Ap0;
    short8 rA1 = *(const short8*)Ap1;
    short8 rB0 = *(const short8*)Bp0;
    short8 rB1 = *(const short8*)Bp1;

    f32x4 acc[4][4] = {};
    for (int k0 = 0; k0 < 512; k0 += 32) {
        if (k0) __syncthreads();
        *(short8*)&As[sr][sc]      = rA0;
        *(short8*)&As[sr + 64][sc] = rA1;
        *(short8*)&Bs[sr][sc]      = rB0;
        *(short8*)&Bs[sr + 64][sc] = rB1;
        __syncthreads();
        if (k0 + 32 < 512) {
            rA0 = *(const short8*)(Ap0 + k0 + 32);
            rA1 = *(const short8*)(Ap1 + k0 + 32);
            rB0 = *(const short8*)(Bp0 + k0 + 32);
            rB1 = *(const short8*)(Bp1 + k0 + 32);
        }
        short8 af[4], bfr[4];
        #pragma unroll
        for (int i = 0; i < 4; i++) af[i] = *(const short8*)&As[wr + i * 16 + l16][quad * 8];
        #pragma unroll
        for (int j = 0; j < 4; j++) bfr[j] = *(const short8*)&Bs[wc + j * 16 + l16][quad * 8];
        #pragma unroll
        for (int i = 0; i < 4; i++)
            #pragma unroll
            for (int j = 0; j < 4; j++)
                acc[i][j] = __builtin_amdgcn_mfma_f32_16x16x32_bf16(af[i], bfr[j], acc[i][j], 0, 0, 0);
    }
    #pragma unroll
    for (int i = 0; i < 4; i++)
        #pragma unroll
        for (int r = 0; r < 4; r++) {
            const int row = m0 + wr + i * 16 + quad * 4 + r;
            #pragma unroll
            for (int j = 0; j < 4; j++) {
                const int col = n0 + wc + j * 16 + l16;
                Ob[(long)row * 768 + col] = f2bf(acc[i][j][r]);
            }
        }
}

// ------------- main projection GEMM: C = cn(256x768) @ Wt(1024x768)^T ------
// col<512: Kq[b][row][col] = C + bKV[col]   (row-major)
// col>=512: Vot[b][col-512][row] = C + bKV[col]  (transposed)
__launch_bounds__(256, 2)
__global__ void gemm_kvq(const u16* __restrict__ cn, const u16* __restrict__ Wt,
                         const float* __restrict__ bKV,
                         u16* __restrict__ Kq, u16* __restrict__ Vot) {
    __shared__ u16 As[128][56];
    __shared__ u16 Bs[128][56];
    const int tid = threadIdx.x;
    const int lane = tid & 63;
    const int wave = tid >> 6;
    const int bb = blockIdx.y;
    const int m0 = (blockIdx.x >> 3) << 7;   // 2 m-tiles (NS=256)
    const int n0 = (blockIdx.x & 7) << 7;    // 8 n-tiles (1024)
    const u16* Ab = cn + (long)bb * NS * CTX + (long)m0 * CTX;
    const u16* Bb = Wt + (long)n0 * CTX;

    const int sr = tid >> 2;
    const int sc = (tid & 3) << 3;
    const int l16 = lane & 15;
    const int quad = lane >> 4;
    const int wr = (wave >> 1) << 6;
    const int wc = (wave & 1) << 6;

    const u16* Ap0 = Ab + (long)sr * CTX + sc;
    const u16* Ap1 = Ab + (long)(sr + 64) * CTX + sc;
    const u16* Bp0 = Bb + (long)sr * CTX + sc;
    const u16* Bp1 = Bb + (long)(sr + 64) * CTX + sc;
    short8 rA0 = *(const short8*)Ap0;
    short8 rA1 = *(const short8*)Ap1;
    short8 rB0 = *(const short8*)Bp0;
    short8 rB1 = *(const short8*)Bp1;

    f32x4 acc[4][4] = {};
    for (int k0 = 0; k0 < CTX; k0 += 32) {
        if (k0) __syncthreads();
        *(short8*)&As[sr][sc]      = rA0;
        *(short8*)&As[sr + 64][sc] = rA1;
        *(short8*)&Bs[sr][sc]      = rB0;
        *(short8*)&Bs[sr + 64][sc] = rB1;
        __syncthreads();
        if (k0 + 32 < CTX) {
            rA0 = *(const short8*)(Ap0 + k0 + 32);
            rA1 = *(const short8*)(Ap1 + k0 + 32);
            rB0 = *(const short8*)(Bp0 + k0 + 32);
            rB1 = *(const short8*)(Bp1 + k0 + 32);
        }
        short8 af[4], bfr[4];
        #pragma unroll
        for (int i = 0; i < 4; i++) af[i] = *(const short8*)&As[wr + i * 16 + l16][quad * 8];
        #pragma unroll
        for (int j = 0; j < 4; j++) bfr[j] = *(const short8*)&Bs[wc + j * 16 + l16][quad * 8];
        #pragma unroll
        for (int i = 0; i < 4; i++)
            #pragma unroll
            for (int j = 0; j < 4; j++)
                acc[i][j] = __builtin_amdgcn_mfma_f32_16x16x32_bf16(af[i], bfr[j], acc[i][j], 0, 0, 0);
    }

    #pragma unroll
    for (int i = 0; i < 4; i++)
        #pragma unroll
        for (int r = 0; r < 4; r++) {
            const int row = m0 + wr + i * 16 + quad * 4 + r;
            #pragma unroll
            for (int j = 0; j < 4; j++) {
                const int col = n0 + wc + j * 16 + l16;
                const u16 v = f2bf(acc[i][j][r] + bKV[col]);
                if (col < DIM) Kq[(long)bb * NS * DIM + (long)row * DIM + col] = v;
                else           Vot[(long)bb * DIM * NS + (long)(col - DIM) * NS + row] = v;
            }
        }
}

// ------------- fused attention: S = xn@Kq^T, softmax, O = P@Vot^T ----------
// block: 512 thr (8 waves, 2m x 4n), 128 q-rows, full NS=256 cols.
// LDS (78080 B -> 2 blocks/CU):
//   [0, 43008)   As 128x56 + Bs 256x56  (S-phase staging, dead after S)
//   [0, 67584)   P 128x264 bf16         (aliases As/Bs; written post-S)
//   [67584, 69632)  red 128x4 f32
//   [69632, 78080)  lbuf 16x132 f32     (epilogue transpose, 512B-run writes)
// S-phase: 2-phase register-prefetch pipeline. V read direct from global (L2).
__launch_bounds__(512, 4)
__global__ void flash_attn(const u16* __restrict__ xnt, const u16* __restrict__ Kq,
                           const u16* __restrict__ Vot, const float* __restrict__ kbias,
                           const float* __restrict__ bo, const float* __restrict__ x,
                           float* __restrict__ out) {
    __shared__ __align__(16) char fsm[78080];
    u16 (*As)[56]      = (u16(*)[56])(fsm);
    u16 (*Bs)[56]      = (u16(*)[56])(fsm + 14336);
    u16 (*P)[264]      = (u16(*)[264])(fsm);            // aliases As/Bs
    float (*red)[4]    = (float(*)[4])(fsm + 67584);
    float (*lbuf)[132] = (float(*)[132])(fsm + 69632);

    const int tid = threadIdx.x;
    const int lane = tid & 63;
    const int wave = tid >> 6;   // 0..7
    const int mw = wave >> 2;    // 0..1  (row group of 64)
    const int nw = wave & 3;     // 0..3  (col group of 64)
    const int l16 = lane & 15;
    const int quad = lane >> 4;
    const int b = blockIdx.y;
    const int m0 = blockIdx.x << 7;

    const u16* Ab = xnt + ((long)b * HW + m0) * DIM;
    const u16* Bb = Kq + (long)b * NS * DIM;

    // ---------------- S phase (pipelined) ----------------
    const int rS = tid >> 2, cS = (tid & 3) << 3;
    const int rB = tid >> 1, cB = (tid & 1) << 4;
    const u16* Ap = Ab + (long)rS * DIM + cS;
    const u16* Bp = Bb + (long)rB * DIM + cB;
    short8 rA  = *(const short8*)(Ap);
    short8 rB0 = *(const short8*)(Bp);
    short8 rB1 = *(const short8*)(Bp + 8);

    f32x4 acc[4][4] = {};
    for (int k0 = 0; k0 < DIM; k0 += 32) {
        if (k0) __syncthreads();          // prior iter's fragment reads done
        *(short8*)&As[rS][cS]     = rA;
        *(short8*)&Bs[rB][cB]     = rB0;
        *(short8*)&Bs[rB][cB + 8] = rB1;
        __syncthreads();
        if (k0 + 32 < DIM) {              // prefetch next tile (hidden under MFMA)
            rA  = *(const short8*)(Ap + k0 + 32);
            rB0 = *(const short8*)(Bp + k0 + 32);
            rB1 = *(const short8*)(Bp + k0 + 40);
        }
        short8 af[4], bfr[4];
        #pragma unroll
        for (int i = 0; i < 4; i++) af[i] = *(const short8*)&As[mw * 64 + i * 16 + l16][quad * 8];
        #pragma unroll
        for (int j = 0; j < 4; j++) bfr[j] = *(const short8*)&Bs[nw * 64 + j * 16 + l16][quad * 8];
        #pragma unroll
        for (int i = 0; i < 4; i++)
            #pragma unroll
            for (int j = 0; j < 4; j++)
                acc[i][j] = __builtin_amdgcn_mfma_f32_16x16x32_bf16(af[i], bfr[j], acc[i][j], 0, 0, 0);
    }

    // ---------------- softmax ----------------
    const float scale = 0.044194173824159216f;
    float kb[4];
    #pragma unroll
    for (int j = 0; j < 4; j++) kb[j] = kbias[b * NS + nw * 64 + j * 16 + l16];

    #pragma unroll
    for (int i = 0; i < 4; i++) {
        #pragma unroll
        for (int r = 0; r < 4; r++) {
            float m = -1e30f;
            #pragma unroll
            for (int j = 0; j < 4; j++) {
                float v = (acc[i][j][r] + kb[j]) * scale;
                acc[i][j][r] = v;
                m = fmaxf(m, v);
            }
            #pragma unroll
            for (int off = 1; off < 16; off <<= 1) m = fmaxf(m, __shfl_xor(m, off));
            if (l16 == 0) red[mw * 64 + i * 16 + quad * 4 + r][nw] = m;
        }
    }
    __syncthreads();
    float rsum[4][4];
    #pragma unroll
    for (int i = 0; i < 4; i++) {
        #pragma unroll
        for (int r = 0; r < 4; r++) {
            const int row = mw * 64 + i * 16 + quad * 4 + r;
            float4 rv = *(const float4*)red[row];
            float gm = fmaxf(fmaxf(rv.x, rv.y), fmaxf(rv.z, rv.w));
            float s = 0.f;
            #pragma unroll
            for (int j = 0; j < 4; j++) {
                float e = __expf(acc[i][j][r] - gm);
                acc[i][j][r] = e;
                s += e;
            }
            #pragma unroll
            for (int off = 1; off < 16; off <<= 1) s += __shfl_xor(s, off);
            rsum[i][r] = s;
        }
    }
    __syncthreads();
    #pragma unroll
    for (int i = 0; i < 4; i++)
        #pragma unroll
        for (int r = 0; r < 4; r++)
            if (l16 == 0) red[mw * 64 + i * 16 + quad * 4 + r][nw] = rsum[i][r];
    __syncthreads();
    #pragma unroll
    for (int i = 0; i < 4; i++) {
        #pragma unroll
        for (int r = 0; r < 4; r++) {
            const int row = mw * 64 + i * 16 + quad * 4 + r;
            float4 sv = *(const float4*)red[row];
            float inv = 1.f / (sv.x + sv.y + sv.z + sv.w);
            #pragma unroll
            for (int j = 0; j < 4; j++)
                P[row][nw * 64 + j * 16 + l16] = f2bf(acc[i][j][r] * inv);
        }
    }
    __syncthreads();   // P ready for all waves

    // -------- PV phase: 4 chunks of 128 out-channels ---------
    const u16* Vb = Vot + ((long)b * DIM + nw * 32 + l16) * NS + quad * 8;
    for (int nc = 0; nc < 4; nc++) {
        f32x4 oacc[4][2];
        #pragma unroll
        for (int i = 0; i < 4; i++)
            #pragma unroll
            for (int jj = 0; jj < 2; jj++)
                oacc[i][jj] = (f32x4){0.f, 0.f, 0.f, 0.f};
        #pragma unroll
        for (int kk = 0; kk < 8; kk++) {
            short8 pf[4], vf[2];
            #pragma unroll
            for (int i = 0; i < 4; i++)
                pf[i] = *(const short8*)&P[mw * 64 + i * 16 + l16][kk * 32 + quad * 8];
            #pragma unroll
            for (int jj = 0; jj < 2; jj++)
                vf[jj] = *(const short8*)(Vb + (long)(nc * 128 + jj * 16) * NS + kk * 32);
            #pragma unroll
            for (int i = 0; i < 4; i++)
                #pragma unroll
                for (int jj = 0; jj < 2; jj++)
                    oacc[i][jj] = __builtin_amdgcn_mfma_f32_16x16x32_bf16(pf[i], vf[jj], oacc[i][jj], 0, 0, 0);
        }
        // epilogue: O chunk (128 p x 128 c), 8 passes of 16 cols via lbuf.
        // 512B-contiguous p-runs per channel row (write-coalescing critical).
        #pragma unroll
        for (int t = 0; t < 8; t++) {
            __syncthreads();   // prior lbuf readers done
            if (nw == (t >> 1)) {
                const int jj = t & 1;
                #pragma unroll
                for (int i = 0; i < 4; i++)
                    #pragma unroll
                    for (int r = 0; r < 4; r++)
                        lbuf[l16][mw * 64 + i * 16 + quad * 4 + r] = oacc[i][jj][r];
            }
            __syncthreads();
            {
                const int cl = tid >> 5;          // 0..15
                const int p4 = (tid & 31) * 4;    // 0..124
                const int cg = nc * 128 + t * 16 + cl;
                const long idx = ((long)b * DIM + cg) * HW + m0 + p4;
                const float bv = bo[cg];
                float4 v0 = *(const float4*)&lbuf[cl][p4];
                float4 x0 = *(const float4*)&x[idx];
                v0.x += x0.x + bv; v0.y += x0.y + bv; v0.z += x0.z + bv; v0.w += x0.w + bv;
                *(float4*)&out[idx] = v0;
            }
        }
    }
}

extern "C" void kernel_launch(void* const* d_in, const int* in_sizes, int n_in,
                              void* d_out, int out_size, void* d_ws, size_t ws_size,
                              hipStream_t stream) {
    const float* x    = (const float*)d_in[0];
    const float* ctx  = (const float*)d_in[1];
    const float* gn_w = (const float*)d_in[2];
    const float* gn_b = (const float*)d_in[3];
    const float* ln_w = (const float*)d_in[4];
    const float* ln_b = (const float*)d_in[5];
    const float* wq   = (const float*)d_in[6];
    const float* bq   = (const float*)d_in[7];
    const float* wkv  = (const float*)d_in[8];
    const float* bkv  = (const float*)d_in[9];
    const float* wo   = (const float*)d_in[10];
    const float* bo   = (const float*)d_in[11];

    char* ws = (char*)d_ws;
    u16*   xnt   = (u16*)(ws + 0);             // 64 MB
    u16*   cn    = (u16*)(ws + 67108864);      //  6 MB
    u16*   Kq    = (u16*)(ws + 73400320);      //  4 MB  (b,s,512)
    u16*   Vot   = (u16*)(ws + 77594624);      //  4 MB  (b,c',s)
    u16*   wqtb  = (u16*)(ws + 81788928);      // 512 KB (wq^T)
    u16*   wob   = (u16*)(ws + 82313216);      // 512 KB
    u16*   wkvtb = (u16*)(ws + 82837504);      // 1.5 MB (wkv^T, [768][1024])
    u16*   Wt    = (u16*)(ws + 84410368);      // 1.5 MB (fused weights [1024][768])
    float* bKV   = (float*)(ws + 85983232);    // 4 KB
    float* wt    = (float*)(ws + 85987328);    // 3 KB
    float* c0    = (float*)(ws + 85990400);    // 4 B
    float* ga    = (float*)(ws + 85991424);    // 32 KB
    float* gd    = ga + NB * DIM;              // 32 KB
    float* kbias = (float*)(ws + 86056960);    // 16 KB

    gn_stats<<<dim3(NB * 32), dim3(256), 0, stream>>>(x, gn_w, gn_b, ga, gd);
    gn_apply_t<<<dim3(512, NB), dim3(256), 0, stream>>>(x, ga, gd, xnt);
    cvt_weights<<<dim3(3072), dim3(256), 0, stream>>>(wq, wkv, wo, wqtb, wkvtb, wob);
    bias_prep<<<dim3(1793), dim3(256), 0, stream>>>(wqtb, wob, wkvtb, bq, bkv, bKV, wt, c0);
    ln_ctx<<<dim3(NB * NS), dim3(256), 0, stream>>>(ctx, ln_w, ln_b, wt, c0, cn, kbias);
    // fused weights: Wt[1024][768] = [wq^T·wkv_k ; wo·wkv_v]
    gemm_wprep<<<dim3(24, 1, 2), dim3(256), 0, stream>>>(wqtb, wob, wkvtb, Wt);
    // Kq / Vot in one GEMM: cn @ Wt^T
    gemm_kvq<<<dim3(2 * 8, NB), dim3(256), 0, stream>>>(cn, Wt, bKV, Kq, Vot);
    // fused sim + softmax + PV + residual -> d_out (b,c,p) fp32
    flash_attn<<<dim3(32, NB), dim3(512), 0, stream>>>(
        xnt, Kq, Vot, kbias, bo, x, (float*)d_out);
}